// Round 1
// 18706.938 us; speedup vs baseline: 1.6327x; 1.6327x over previous
//
#include <hip/hip_runtime.h>
#include <math.h>

// Problem constants: S=1024, B=64, I=512, H=512, 2 layers, fp32.
#define SEQ 1024
#define BATCH 64
#define HID 512
#define MROWS (SEQ * BATCH)   // 65536

// Recurrence decomposition
#define SLICES 8              // j-slices per batch group
#define JW 64                 // output columns per block
#define NGROUPS 32            // batch pairs
#define BAR_STRIDE 16         // uints per group flag (64B padding, no false sharing)

// ---------------------------------------------------------------------------
// Transpose W_hh (H,H) row-major (j,k) -> Wt[k*H + j].
// ---------------------------------------------------------------------------
__launch_bounds__(256)
__global__ void transposeW(const float* __restrict__ W, float* __restrict__ Wt) {
    __shared__ float tile[32][33];
    int bx = blockIdx.x % 16;           // col-tile
    int by = blockIdx.x / 16;           // row-tile
    int tx = threadIdx.x % 32;
    int ty = threadIdx.x / 32;          // 0..7
    #pragma unroll
    for (int i = 0; i < 32; i += 8)
        tile[ty + i][tx] = W[(size_t)(by * 32 + ty + i) * HID + bx * 32 + tx];
    __syncthreads();
    #pragma unroll
    for (int i = 0; i < 32; i += 8)
        Wt[(size_t)(bx * 32 + ty + i) * HID + by * 32 + tx] = tile[tx][ty + i];
}

// ---------------------------------------------------------------------------
// C[i,j] = sum_k A[i,k] * W[j,k] + b1[j] + b2[j]
// Tiled fp32 GEMM: 64x64 tile per 256-thread block, BK=16, 4x4 micro-tile.
// ---------------------------------------------------------------------------
#define BM 64
#define BN 64
#define BK 16
__launch_bounds__(256)
__global__ void gemm_bias(const float* __restrict__ A, const float* __restrict__ W,
                          const float* __restrict__ b1, const float* __restrict__ b2,
                          float* __restrict__ C) {
    __shared__ float As[BK][BM + 4];
    __shared__ float Ws[BK][BN + 4];

    const int bj = blockIdx.x % (HID / BN);   // 0..7
    const int bi = blockIdx.x / (HID / BN);   // 0..1023
    const int tid = threadIdx.x;
    const int tx = tid % 16;
    const int ty = tid / 16;
    const int row0 = bi * BM;
    const int col0 = bj * BN;

    const int lr = tid / 4;              // 0..63  (tile row)
    const int lk = (tid % 4) * 4;        // 0,4,8,12 (k offset)

    float acc[4][4] = {};

    for (int k0 = 0; k0 < HID; k0 += BK) {
        float4 av = *(const float4*)(A + (size_t)(row0 + lr) * HID + k0 + lk);
        float4 wv = *(const float4*)(W + (size_t)(col0 + lr) * HID + k0 + lk);
        As[lk + 0][lr] = av.x; As[lk + 1][lr] = av.y;
        As[lk + 2][lr] = av.z; As[lk + 3][lr] = av.w;
        Ws[lk + 0][lr] = wv.x; Ws[lk + 1][lr] = wv.y;
        Ws[lk + 2][lr] = wv.z; Ws[lk + 3][lr] = wv.w;
        __syncthreads();
        #pragma unroll
        for (int k = 0; k < BK; ++k) {
            float4 a = *(const float4*)&As[k][ty * 4];
            float4 w = *(const float4*)&Ws[k][tx * 4];
            acc[0][0] += a.x * w.x; acc[0][1] += a.x * w.y; acc[0][2] += a.x * w.z; acc[0][3] += a.x * w.w;
            acc[1][0] += a.y * w.x; acc[1][1] += a.y * w.y; acc[1][2] += a.y * w.z; acc[1][3] += a.y * w.w;
            acc[2][0] += a.z * w.x; acc[2][1] += a.z * w.y; acc[2][2] += a.z * w.z; acc[2][3] += a.z * w.w;
            acc[3][0] += a.w * w.x; acc[3][1] += a.w * w.y; acc[3][2] += a.w * w.z; acc[3][3] += a.w * w.w;
        }
        __syncthreads();
    }

    #pragma unroll
    for (int c = 0; c < 4; ++c) {
        int col = col0 + tx * 4 + c;
        float bias = b1[col] + b2[col];
        #pragma unroll
        for (int r = 0; r < 4; ++r) {
            C[(size_t)(row0 + ty * 4 + r) * HID + col] = acc[r][c] + bias;
        }
    }
}

// ---------------------------------------------------------------------------
// Distributed recurrence.
// Grid: 256 blocks = 32 batch-pairs x 8 j-slices. 1024 threads.
// Each block keeps Ws[512][64] (its W_hh^T column slice) resident in LDS and
// computes out[j0..j0+63] for 2 batch elements each step. The 8 slice-blocks
// of a batch pair exchange h through double-buffered global hbuf with
// agent-scope atomics + a monotonic release/acquire counter barrier.
// LDS = 128KB Ws + 4KB hs + 8KB red = 140KB -> exactly 1 block/CU, grid=256
// = #CUs, so all blocks are co-resident (no spin deadlock).
// ---------------------------------------------------------------------------
__launch_bounds__(1024, 4)
__global__ void rnn_rec2(float* __restrict__ U,            // (S,B,H) in/out (y written in place)
                         const float* __restrict__ Wt,     // (H,H): Wt[k*H + j] = W_hh[j,k]
                         const float* __restrict__ h0,     // (B,H)
                         float* __restrict__ hT,           // (B,H)
                         float* __restrict__ hbuf,         // (2,B,H) exchange buffer
                         unsigned int* __restrict__ bar)   // (NGROUPS*BAR_STRIDE), zeroed
{
    __shared__ float  Ws[HID][JW];       // 128 KB, bank-clean: lane=j -> 2-way (free)
    __shared__ float2 hs[HID];           // 4 KB: (h[b0][k], h[b1][k])
    __shared__ float2 red[16][JW];       // 8 KB: per-kq partials

    const int g  = blockIdx.x >> 3;      // batch pair 0..31
    const int s  = blockIdx.x & 7;       // j slice 0..7
    const int j0 = s * JW;
    const int b0 = g * 2;
    const int tid = threadIdx.x;
    const int jl = tid & 63;             // lane = output column
    const int kq = tid >> 6;             // 0..15: k-quarter (32 k's each)

    // ---- load W slice into LDS (one-time) ----
    for (int k = kq * 32; k < kq * 32 + 32; ++k)
        Ws[k][jl] = Wt[(size_t)k * HID + j0 + jl];

    // ---- initial hidden state ----
    if (tid < HID)
        hs[tid] = make_float2(h0[(size_t)b0 * HID + tid],
                              h0[(size_t)(b0 + 1) * HID + tid]);
    __syncthreads();

    // reducer-thread identity (valid for tid < 128)
    const int rb = tid >> 6;             // batch within pair (0/1)
    const int rj = tid & 63;             // output column
    float u_pref = 0.f;
    if (tid < 128)
        u_pref = U[((size_t)0 * BATCH + (b0 + rb)) * HID + j0 + rj];

    for (int t = 0; t < SEQ; ++t) {
        // ---- partial dot products: 32 k's x 2 batches per thread ----
        float a0 = 0.f, a1 = 0.f;
        const float*  wcol = &Ws[kq * 32][jl];   // stride 64 floats
        const float2* hrow = &hs[kq * 32];
        #pragma unroll 8
        for (int kk = 0; kk < 32; ++kk) {
            float  w  = wcol[kk * 64];           // ds_read_b32, conflict-free
            float2 h2 = hrow[kk];                // broadcast read
            a0 = fmaf(w, h2.x, a0);
            a1 = fmaf(w, h2.y, a1);
        }
        red[kq][jl] = make_float2(a0, a1);
        __syncthreads();

        const int p = (t + 1) & 1;               // double-buffer parity

        // ---- reduce + tanh + publish (2 waves) ----
        if (tid < 128) {
            float sum = 0.f;
            const float* rp = (const float*)red;
            #pragma unroll
            for (int q = 0; q < 16; ++q)
                sum += rp[(q * 64 + rj) * 2 + rb];
            float v = tanhf(u_pref + sum);
            const size_t ybase = ((size_t)t * BATCH + (b0 + rb)) * HID + j0 + rj;
            U[ybase] = v;                        // y output, in place
            __hip_atomic_store(&hbuf[((size_t)p * BATCH + (b0 + rb)) * HID + j0 + rj], v,
                               __ATOMIC_RELAXED, __HIP_MEMORY_SCOPE_AGENT);
            const int tn = (t + 1 < SEQ) ? (t + 1) : t;
            u_pref = U[((size_t)tn * BATCH + (b0 + rb)) * HID + j0 + rj];  // prefetch next U
        }
        __syncthreads();   // drains vmcnt: all h-stores at coherence point

        // ---- group barrier: monotonic counter, release/acquire ----
        if (tid == 0) {
            __hip_atomic_fetch_add(&bar[g * BAR_STRIDE], 1u,
                                   __ATOMIC_ACQ_REL, __HIP_MEMORY_SCOPE_AGENT);
            const unsigned int tgt = 8u * (unsigned)(t + 1);
            int guard = 0;
            while (__hip_atomic_load(&bar[g * BAR_STRIDE],
                                     __ATOMIC_ACQUIRE, __HIP_MEMORY_SCOPE_AGENT) < tgt) {
                if (++guard > (1 << 25)) break;  // safety valve: fail, don't hang
            }
        }
        __syncthreads();

        // ---- gather full h_{t+1} (1024 values, 1 per thread) ----
        {
            const int bb = tid >> 9;             // 0..1
            const int k  = tid & 511;
            float v = __hip_atomic_load(&hbuf[((size_t)p * BATCH + (b0 + bb)) * HID + k],
                                        __ATOMIC_RELAXED, __HIP_MEMORY_SCOPE_AGENT);
            ((float*)hs)[k * 2 + bb] = v;
        }
        __syncthreads();
    }

    // ---- final hidden state (slice 0 blocks hold full hs like everyone) ----
    if (s == 0 && tid < HID) {
        hT[(size_t)(b0 + 0) * HID + tid] = hs[tid].x;
        hT[(size_t)(b0 + 1) * HID + tid] = hs[tid].y;
    }
}

// ---------------------------------------------------------------------------
// Launch
// ---------------------------------------------------------------------------
extern "C" void kernel_launch(void* const* d_in, const int* in_sizes, int n_in,
                              void* d_out, int out_size, void* d_ws, size_t ws_size,
                              hipStream_t stream) {
    (void)in_sizes; (void)n_in; (void)out_size; (void)ws_size;

    const float* x      = (const float*)d_in[0];   // (S,B,I)
    const float* hx     = (const float*)d_in[1];   // (2,B,H)
    const float* W_ih0  = (const float*)d_in[2];   // (H,I)
    const float* W_hh0  = (const float*)d_in[3];   // (H,H)
    const float* b_ih0  = (const float*)d_in[4];   // (H,)
    const float* b_hh0  = (const float*)d_in[5];   // (H,)
    const float* W_ih1  = (const float*)d_in[6];   // (H,H)
    const float* W_hh1  = (const float*)d_in[7];   // (H,H)
    const float* b_ih1  = (const float*)d_in[8];   // (H,)
    const float* b_hh1  = (const float*)d_in[9];   // (H,)

    float* out = (float*)d_out;
    float* y1   = out;                                  // (S,B,H)
    float* hT0  = out + (size_t)SEQ * BATCH * HID;      // (B,H)
    float* hT1  = hT0 + (size_t)BATCH * HID;            // (B,H)

    // Workspace: Wt0 (1MB) | Wt1 (1MB) | hbuf (256KB) | bar0+bar1 (4KB) | U0 (128MB)
    float* Wt0  = (float*)d_ws;
    float* Wt1  = Wt0 + (size_t)HID * HID;
    float* hbuf = Wt1 + (size_t)HID * HID;
    unsigned int* bar0 = (unsigned int*)(hbuf + (size_t)2 * BATCH * HID);
    unsigned int* bar1 = bar0 + NGROUPS * BAR_STRIDE;
    float* U0   = (float*)(bar1 + NGROUPS * BAR_STRIDE);

    // zero both barrier regions (re-done every launch; graph-capture safe)
    hipMemsetAsync(bar0, 0, 2 * NGROUPS * BAR_STRIDE * sizeof(unsigned int), stream);

    // 1. transpose W_hh for both layers
    transposeW<<<256, 256, 0, stream>>>(W_hh0, Wt0);
    transposeW<<<256, 256, 0, stream>>>(W_hh1, Wt1);

    // 2. Layer 0 input GEMM: U0 = x @ W_ih0^T + b_ih0 + b_hh0
    gemm_bias<<<(MROWS / BM) * (HID / BN), 256, 0, stream>>>(x, W_ih0, b_ih0, b_hh0, U0);

    // 3. Layer 0 recurrence (distributed, LDS-resident W)
    rnn_rec2<<<NGROUPS * SLICES, 1024, 0, stream>>>(U0, Wt0, hx, hT0, hbuf, bar0);

    // 4. Layer 1 input GEMM: y1 = y0 @ W_ih1^T + b_ih1 + b_hh1
    gemm_bias<<<(MROWS / BM) * (HID / BN), 256, 0, stream>>>(U0, W_ih1, b_ih1, b_hh1, y1);

    // 5. Layer 1 recurrence
    rnn_rec2<<<NGROUPS * SLICES, 1024, 0, stream>>>(y1, Wt1, hx + (size_t)BATCH * HID, hT1, hbuf, bar1);
}

// Round 2
// 5633.825 us; speedup vs baseline: 5.4215x; 3.3205x over previous
//
#include <hip/hip_runtime.h>
#include <math.h>

// Problem constants: S=1024, B=64, I=512, H=512, 2 layers, fp32.
#define SEQ 1024
#define BATCH 64
#define HID 512
#define MROWS (SEQ * BATCH)   // 65536

// Recurrence decomposition
#define SLICES 8              // j-slices per batch group
#define JW 64                 // output columns per block
#define NGROUPS 32            // batch pairs
#define SENT 0x7F7F7F7Fu      // sentinel bits (3.39e38f; tanh output can never equal it)

// ---------------------------------------------------------------------------
// Transpose W_hh (H,H) row-major (j,k) -> Wt[k*H + j].
// ---------------------------------------------------------------------------
__launch_bounds__(256)
__global__ void transposeW(const float* __restrict__ W, float* __restrict__ Wt) {
    __shared__ float tile[32][33];
    int bx = blockIdx.x % 16;           // col-tile
    int by = blockIdx.x / 16;           // row-tile
    int tx = threadIdx.x % 32;
    int ty = threadIdx.x / 32;          // 0..7
    #pragma unroll
    for (int i = 0; i < 32; i += 8)
        tile[ty + i][tx] = W[(size_t)(by * 32 + ty + i) * HID + bx * 32 + tx];
    __syncthreads();
    #pragma unroll
    for (int i = 0; i < 32; i += 8)
        Wt[(size_t)(bx * 32 + ty + i) * HID + by * 32 + tx] = tile[tx][ty + i];
}

// ---------------------------------------------------------------------------
// C[i,j] = sum_k A[i,k] * W[j,k] + b1[j] + b2[j]
// Tiled fp32 GEMM: 64x64 tile per 256-thread block, BK=16, 4x4 micro-tile.
// ---------------------------------------------------------------------------
#define BM 64
#define BN 64
#define BK 16
__launch_bounds__(256)
__global__ void gemm_bias(const float* __restrict__ A, const float* __restrict__ W,
                          const float* __restrict__ b1, const float* __restrict__ b2,
                          float* __restrict__ C) {
    __shared__ float As[BK][BM + 4];
    __shared__ float Ws[BK][BN + 4];

    const int bj = blockIdx.x % (HID / BN);   // 0..7
    const int bi = blockIdx.x / (HID / BN);   // 0..1023
    const int tid = threadIdx.x;
    const int tx = tid % 16;
    const int ty = tid / 16;
    const int row0 = bi * BM;
    const int col0 = bj * BN;

    const int lr = tid / 4;              // 0..63  (tile row)
    const int lk = (tid % 4) * 4;        // 0,4,8,12 (k offset)

    float acc[4][4] = {};

    for (int k0 = 0; k0 < HID; k0 += BK) {
        float4 av = *(const float4*)(A + (size_t)(row0 + lr) * HID + k0 + lk);
        float4 wv = *(const float4*)(W + (size_t)(col0 + lr) * HID + k0 + lk);
        As[lk + 0][lr] = av.x; As[lk + 1][lr] = av.y;
        As[lk + 2][lr] = av.z; As[lk + 3][lr] = av.w;
        Ws[lk + 0][lr] = wv.x; Ws[lk + 1][lr] = wv.y;
        Ws[lk + 2][lr] = wv.z; Ws[lk + 3][lr] = wv.w;
        __syncthreads();
        #pragma unroll
        for (int k = 0; k < BK; ++k) {
            float4 a = *(const float4*)&As[k][ty * 4];
            float4 w = *(const float4*)&Ws[k][tx * 4];
            acc[0][0] += a.x * w.x; acc[0][1] += a.x * w.y; acc[0][2] += a.x * w.z; acc[0][3] += a.x * w.w;
            acc[1][0] += a.y * w.x; acc[1][1] += a.y * w.y; acc[1][2] += a.y * w.z; acc[1][3] += a.y * w.w;
            acc[2][0] += a.z * w.x; acc[2][1] += a.z * w.y; acc[2][2] += a.z * w.z; acc[2][3] += a.z * w.w;
            acc[3][0] += a.w * w.x; acc[3][1] += a.w * w.y; acc[3][2] += a.w * w.z; acc[3][3] += a.w * w.w;
        }
        __syncthreads();
    }

    #pragma unroll
    for (int c = 0; c < 4; ++c) {
        int col = col0 + tx * 4 + c;
        float bias = b1[col] + b2[col];
        #pragma unroll
        for (int r = 0; r < 4; ++r) {
            C[(size_t)(row0 + ty * 4 + r) * HID + col] = acc[r][c] + bias;
        }
    }
}

// ---------------------------------------------------------------------------
// hbuf slot index. Layout: [parity][group][consumer][producer][rb][rj]
// Consumer's gather region is contiguous per producer chunk (coalesced polls);
// each slot has exactly ONE producer lane and ONE consumer lane.
// ---------------------------------------------------------------------------
__device__ __forceinline__ size_t hb_idx(int p, int g, int cons, int prod, int rb, int rj) {
    return ((((size_t)((p * NGROUPS + g) * SLICES + cons) * SLICES + prod) * 2 + rb) * JW) + rj;
}

// ---------------------------------------------------------------------------
// Distributed recurrence, sentinel-flag exchange (no counter barrier).
// Grid: 256 blocks = 32 batch-pairs x 8 j-slices. 1024 threads.
// Per step: 16 waves compute partials from LDS-resident W slice; 2 reducer
// waves reduce+tanh and publish each value to 8 per-consumer slots; 14
// gatherer waves (896 threads = 896 foreign values) spin on their private
// slots (data IS the flag), reset to sentinel, write double-buffered hs.
// Chain per step ~= 1 coherence round trip instead of 4.
// LDS = 128KB Ws + 8KB hs(x2) + 8KB red = 144KB -> 1 block/CU, grid = #CUs.
// ---------------------------------------------------------------------------
__launch_bounds__(1024, 4)
__global__ void rnn_rec3(float* __restrict__ U,            // (S,B,H) in/out (y written in place)
                         const float* __restrict__ Wt,     // (H,H): Wt[k*H + j] = W_hh[j,k]
                         const float* __restrict__ h0,     // (B,H)
                         float* __restrict__ hT,           // (B,H)
                         unsigned int* __restrict__ hb)    // exchange buffer, pre-set to SENT
{
    __shared__ float  Ws[HID][JW];       // 128 KB
    __shared__ float2 hsA[HID], hsB[HID];// 2x4 KB double-buffered hidden state
    __shared__ float2 red[16][JW];       // 8 KB partials

    const int g  = blockIdx.x >> 3;      // batch pair 0..31
    const int s  = blockIdx.x & 7;       // j slice 0..7
    const int j0 = s * JW;
    const int b0 = g * 2;
    const int tid = threadIdx.x;
    const int jl = tid & 63;             // lane = output column
    const int kq = tid >> 6;             // 0..15: k-quarter (32 k's each)

    // ---- load W slice into LDS (one-time) ----
    for (int k = kq * 32; k < kq * 32 + 32; ++k)
        Ws[k][jl] = Wt[(size_t)k * HID + j0 + jl];

    // ---- initial hidden state ----
    if (tid < HID)
        hsA[tid] = make_float2(h0[(size_t)b0 * HID + tid],
                               h0[(size_t)(b0 + 1) * HID + tid]);
    __syncthreads();

    float2* cur = hsA;
    float2* nxt = hsB;

    // reducer identity (tid < 128)
    const int rb = tid >> 6;             // batch within pair
    const int rj = tid & 63;             // output column
    // gatherer identity (tid >= 128): 896 threads <-> 7 foreign producers x 128
    const int fid = tid - 128;
    const int fp  = fid >> 7;                       // 0..6
    const int pp  = fp + (fp >= s ? 1 : 0);         // foreign producer slice
    const int rbb = (fid >> 6) & 1;
    const int rjj = fid & 63;

    float u_pref = 0.f;
    if (tid < 128)
        u_pref = U[((size_t)0 * BATCH + (b0 + rb)) * HID + j0 + rj];

    for (int t = 0; t < SEQ; ++t) {
        // ---- partial dot products: 32 k's x 2 batches per thread ----
        float a0 = 0.f, a1 = 0.f;
        const float*  wcol = &Ws[kq * 32][jl];   // lane-consecutive: conflict-free
        const float2* hrow = &cur[kq * 32];
        #pragma unroll 8
        for (int kk = 0; kk < 32; ++kk) {
            float  w  = wcol[kk * 64];
            float2 h2 = hrow[kk];                // broadcast
            a0 = fmaf(w, h2.x, a0);
            a1 = fmaf(w, h2.y, a1);
        }
        red[kq][jl] = make_float2(a0, a1);
        __syncthreads();

        const int p = (t + 1) & 1;               // exchange-buffer parity

        if (tid < 128) {
            // ---- reduce + tanh + publish ----
            float sum = 0.f;
            const float* rp = (const float*)red;
            #pragma unroll
            for (int q = 0; q < 16; ++q)
                sum += rp[(q * 64 + rj) * 2 + rb];
            float v = tanhf(u_pref + sum);
            const size_t ybase = ((size_t)t * BATCH + (b0 + rb)) * HID + j0 + rj;
            U[ybase] = v;                        // y output, in place
            const unsigned int vb = __float_as_uint(v);
            #pragma unroll
            for (int c = 0; c < SLICES; ++c)     // 8 private consumer copies
                __hip_atomic_store(hb + hb_idx(p, g, c, s, rb, rj), vb,
                                   __ATOMIC_RELAXED, __HIP_MEMORY_SCOPE_AGENT);
            ((float*)nxt)[(j0 + rj) * 2 + rb] = v;   // own slice -> LDS directly
            const int tn = (t + 1 < SEQ) ? (t + 1) : t;
            u_pref = U[((size_t)tn * BATCH + (b0 + rb)) * HID + j0 + rj];  // prefetch
        } else {
            // ---- spin-gather private slot; data IS the flag ----
            unsigned int* slot = hb + hb_idx(p, g, s, pp, rbb, rjj);
            unsigned int bits;
            int guard = 0;
            do {
                bits = __hip_atomic_load(slot, __ATOMIC_RELAXED, __HIP_MEMORY_SCOPE_AGENT);
            } while (bits == SENT && ++guard < (1 << 20));   // fail, don't hang
            __hip_atomic_store(slot, SENT, __ATOMIC_RELAXED, __HIP_MEMORY_SCOPE_AGENT);
            ((float*)nxt)[(pp * JW + rjj) * 2 + rbb] = __uint_as_float(bits);
        }
        __syncthreads();   // drains vmcnt: publishes/resets at coherence point
        float2* tmp = cur; cur = nxt; nxt = tmp;
    }

    // ---- final hidden state ----
    if (s == 0 && tid < HID) {
        hT[(size_t)(b0 + 0) * HID + tid] = cur[tid].x;
        hT[(size_t)(b0 + 1) * HID + tid] = cur[tid].y;
    }
}

// ---------------------------------------------------------------------------
// Launch
// ---------------------------------------------------------------------------
extern "C" void kernel_launch(void* const* d_in, const int* in_sizes, int n_in,
                              void* d_out, int out_size, void* d_ws, size_t ws_size,
                              hipStream_t stream) {
    (void)in_sizes; (void)n_in; (void)out_size; (void)ws_size;

    const float* x      = (const float*)d_in[0];   // (S,B,I)
    const float* hx     = (const float*)d_in[1];   // (2,B,H)
    const float* W_ih0  = (const float*)d_in[2];   // (H,I)
    const float* W_hh0  = (const float*)d_in[3];   // (H,H)
    const float* b_ih0  = (const float*)d_in[4];   // (H,)
    const float* b_hh0  = (const float*)d_in[5];   // (H,)
    const float* W_ih1  = (const float*)d_in[6];   // (H,H)
    const float* W_hh1  = (const float*)d_in[7];   // (H,H)
    const float* b_ih1  = (const float*)d_in[8];   // (H,)
    const float* b_hh1  = (const float*)d_in[9];   // (H,)

    float* out = (float*)d_out;
    float* y1   = out;                                  // (S,B,H)
    float* hT0  = out + (size_t)SEQ * BATCH * HID;      // (B,H)
    float* hT1  = hT0 + (size_t)BATCH * HID;            // (B,H)

    // hbuf: [2][G][cons=8][prod=8][2][64] floats = 2MB per layer
    const size_t HB_ELTS = (size_t)2 * NGROUPS * SLICES * SLICES * 2 * JW;

    // Workspace: Wt0 (1MB) | Wt1 (1MB) | hb0 (2MB) | hb1 (2MB) | U0 (128MB)
    float* Wt0 = (float*)d_ws;
    float* Wt1 = Wt0 + (size_t)HID * HID;
    unsigned int* hb0 = (unsigned int*)(Wt1 + (size_t)HID * HID);
    unsigned int* hb1 = hb0 + HB_ELTS;
    float* U0  = (float*)(hb1 + HB_ELTS);

    // sentinel-fill both exchange buffers (0x7F7F7F7F per word)
    hipMemsetAsync(hb0, 0x7F, 2 * HB_ELTS * sizeof(unsigned int), stream);

    // 1. transpose W_hh for both layers
    transposeW<<<256, 256, 0, stream>>>(W_hh0, Wt0);
    transposeW<<<256, 256, 0, stream>>>(W_hh1, Wt1);

    // 2. Layer 0 input GEMM: U0 = x @ W_ih0^T + b_ih0 + b_hh0
    gemm_bias<<<(MROWS / BM) * (HID / BN), 256, 0, stream>>>(x, W_ih0, b_ih0, b_hh0, U0);

    // 3. Layer 0 recurrence
    rnn_rec3<<<NGROUPS * SLICES, 1024, 0, stream>>>(U0, Wt0, hx, hT0, hb0);

    // 4. Layer 1 input GEMM: y1 = y0 @ W_ih1^T + b_ih1 + b_hh1
    gemm_bias<<<(MROWS / BM) * (HID / BN), 256, 0, stream>>>(U0, W_ih1, b_ih1, b_hh1, y1);

    // 5. Layer 1 recurrence
    rnn_rec3<<<NGROUPS * SLICES, 1024, 0, stream>>>(y1, Wt1, hx + (size_t)BATCH * HID, hT1, hb1);
}

// Round 4
// 3847.290 us; speedup vs baseline: 7.9390x; 1.4644x over previous
//
#include <hip/hip_runtime.h>
#include <math.h>

// Problem constants: S=1024, B=64, I=512, H=512, 2 layers, fp32.
#define SEQ 1024
#define BATCH 64
#define HID 512
#define MROWS (SEQ * BATCH)   // 65536

// Recurrence decomposition
#define SLICES 8              // j-slices per batch group
#define JW 64                 // output columns per block
#define NGROUPS 32            // batch pairs
#define PSTRIDE ((size_t)NGROUPS * SLICES * 2 * JW)   // 32768 u64 slots per parity

typedef unsigned long long u64;
typedef unsigned int u32;

// ---------------------------------------------------------------------------
// Transpose W_hh (H,H) row-major (j,k) -> Wt[k*H + j].
// ---------------------------------------------------------------------------
__launch_bounds__(256)
__global__ void transposeW(const float* __restrict__ W, float* __restrict__ Wt) {
    __shared__ float tile[32][33];
    int bx = blockIdx.x % 16;           // col-tile
    int by = blockIdx.x / 16;           // row-tile
    int tx = threadIdx.x % 32;
    int ty = threadIdx.x / 32;          // 0..7
    #pragma unroll
    for (int i = 0; i < 32; i += 8)
        tile[ty + i][tx] = W[(size_t)(by * 32 + ty + i) * HID + bx * 32 + tx];
    __syncthreads();
    #pragma unroll
    for (int i = 0; i < 32; i += 8)
        Wt[(size_t)(bx * 32 + ty + i) * HID + by * 32 + tx] = tile[tx][ty + i];
}

// ---------------------------------------------------------------------------
// C[i,j] = sum_k A[i,k] * W[j,k] + b1[j] + b2[j]
// Tiled fp32 GEMM: 64x64 tile per 256-thread block, BK=16, 4x4 micro-tile.
// ---------------------------------------------------------------------------
#define BM 64
#define BN 64
#define BK 16
__launch_bounds__(256)
__global__ void gemm_bias(const float* __restrict__ A, const float* __restrict__ W,
                          const float* __restrict__ b1, const float* __restrict__ b2,
                          float* __restrict__ C) {
    __shared__ float As[BK][BM + 4];
    __shared__ float Ws[BK][BN + 4];

    const int bj = blockIdx.x % (HID / BN);   // 0..7
    const int bi = blockIdx.x / (HID / BN);   // 0..1023
    const int tid = threadIdx.x;
    const int tx = tid % 16;
    const int ty = tid / 16;
    const int row0 = bi * BM;
    const int col0 = bj * BN;

    const int lr = tid / 4;              // 0..63  (tile row)
    const int lk = (tid % 4) * 4;        // 0,4,8,12 (k offset)

    float acc[4][4] = {};

    for (int k0 = 0; k0 < HID; k0 += BK) {
        float4 av = *(const float4*)(A + (size_t)(row0 + lr) * HID + k0 + lk);
        float4 wv = *(const float4*)(W + (size_t)(col0 + lr) * HID + k0 + lk);
        As[lk + 0][lr] = av.x; As[lk + 1][lr] = av.y;
        As[lk + 2][lr] = av.z; As[lk + 3][lr] = av.w;
        Ws[lk + 0][lr] = wv.x; Ws[lk + 1][lr] = wv.y;
        Ws[lk + 2][lr] = wv.z; Ws[lk + 3][lr] = wv.w;
        __syncthreads();
        #pragma unroll
        for (int k = 0; k < BK; ++k) {
            float4 a = *(const float4*)&As[k][ty * 4];
            float4 w = *(const float4*)&Ws[k][tx * 4];
            acc[0][0] += a.x * w.x; acc[0][1] += a.x * w.y; acc[0][2] += a.x * w.z; acc[0][3] += a.x * w.w;
            acc[1][0] += a.y * w.x; acc[1][1] += a.y * w.y; acc[1][2] += a.y * w.z; acc[1][3] += a.y * w.w;
            acc[2][0] += a.z * w.x; acc[2][1] += a.z * w.y; acc[2][2] += a.z * w.z; acc[2][3] += a.z * w.w;
            acc[3][0] += a.w * w.x; acc[3][1] += a.w * w.y; acc[3][2] += a.w * w.z; acc[3][3] += a.w * w.w;
        }
        __syncthreads();
    }

    #pragma unroll
    for (int c = 0; c < 4; ++c) {
        int col = col0 + tx * 4 + c;
        float bias = b1[col] + b2[col];
        #pragma unroll
        for (int r = 0; r < 4; ++r) {
            C[(size_t)(row0 + ty * 4 + r) * HID + col] = acc[r][c] + bias;
        }
    }
}

// ---------------------------------------------------------------------------
// Distributed recurrence, tagged-packet exchange (agent-scope atomics only).
// Grid 256 = 32 groups x 8 slices, 1024 threads = 16 waves.
// Slot layout per layer: [parity][group][prod][rb][rj] u64 = (tag | preact).
// Each wave autonomously polls the 64 h-values its k-range needs (lane l ->
// k = 32*kq + (l>>1), b = l&1), tanh's them, shares via a wave-private LDS
// row (same-wave ds ordering, no block barrier), then FMAs with W held in
// registers. Producers (2 waves) reduce partials, publish pre-tanh packets.
// Parity double-buffer + exact-tag match make the exchange race-free; slots
// are zeroed every launch and all stores are agent-scope (write-through), so
// no stale-line ABA across timed iterations.
// ---------------------------------------------------------------------------
__launch_bounds__(1024, 4)
__global__ void rnn_rec5(float* __restrict__ U,            // (S,B,H) in/out
                         const float* __restrict__ Wt,     // (H,H): Wt[k*H+j]
                         const float* __restrict__ h0,     // (B,H)
                         float* __restrict__ hT,           // (B,H)
                         u64* __restrict__ hb)             // slots, zeroed per launch
{
    __shared__ __align__(16) float scratch[16][64];  // per-wave h chunk (k-major, b interleaved)
    __shared__ float2 red[16][JW];                   // 8 KB partials
    __shared__ float  own[2][JW];                    // own-slice h (tanh'd)

    const int blk = blockIdx.x;
    const int s = blk >> 5;              // slice 0..7
    const int g = blk & 31;              // group 0..31 (8 slice-blocks share blk%8)
    const int j0 = s * JW;
    const int b0 = g * 2;
    const int tid = threadIdx.x;
    const int jl = tid & 63;             // lane
    const int kq = tid >> 6;             // wave = k-chunk of 32

    // ---- W slice into registers: thread (kq,jl) owns Wt[32kq+kk][j0+jl] ----
    float wreg[32];
    #pragma unroll
    for (int kk = 0; kk < 32; ++kk)
        wreg[kk] = Wt[(size_t)(kq * 32 + kk) * HID + j0 + jl];   // coalesced

    // ---- gather identity: lane owns h-value (gk, gb) ----
    const int gk = kq * 32 + (jl >> 1);
    const int gb = jl & 1;
    const bool ownwave = ((kq >> 1) == s);
    const size_t gslot = (((size_t)g * SLICES + (gk >> 6)) * 2 + gb) * JW + (gk & 63);

    // ---- init scratch with h_0 (one-time) ----
    scratch[kq][jl] = h0[(size_t)(b0 + gb) * HID + gk];

    // ---- producer identity (tid < 128) ----
    const int rb = (tid >> 6) & 1;
    const int rj = tid & 63;
    float u_pref = 0.f;
    if (tid < 128)
        u_pref = U[((size_t)0 * BATCH + (b0 + rb)) * HID + j0 + rj];

    for (int t = 0; t < SEQ; ++t) {
        // ---- phase 1: partial dot from wave-private scratch, W in regs ----
        float a0 = 0.f, a1 = 0.f;
        const float4* h4p = (const float4*)scratch[kq];
        #pragma unroll
        for (int q = 0; q < 16; ++q) {
            float4 h4 = h4p[q];                  // (b0,b1) for 2 consecutive k
            a0 = fmaf(wreg[2 * q],     h4.x, a0);
            a1 = fmaf(wreg[2 * q],     h4.y, a1);
            a0 = fmaf(wreg[2 * q + 1], h4.z, a0);
            a1 = fmaf(wreg[2 * q + 1], h4.w, a1);
        }
        red[kq][jl] = make_float2(a0, a1);
        __syncthreads();

        const int p = (t + 1) & 1;
        const u32 tag = (u32)(t + 1);

        // ---- phase 2: reduce + publish pre-tanh + local outputs ----
        if (tid < 128) {
            float sum = 0.f;
            const float* rp = (const float*)red;
            #pragma unroll
            for (int q = 0; q < 16; ++q)
                sum += rp[(q * 64 + rj) * 2 + rb];
            float pre = u_pref + sum;
            u64 pkt = ((u64)__float_as_uint(pre) << 32) | tag;
            __hip_atomic_store(hb + p * PSTRIDE
                                  + (((size_t)g * SLICES + s) * 2 + rb) * JW + rj,
                               pkt, __ATOMIC_RELAXED, __HIP_MEMORY_SCOPE_AGENT);
            float v = tanhf(pre);
            U[((size_t)t * BATCH + (b0 + rb)) * HID + j0 + rj] = v;  // y output
            own[rb][rj] = v;
            const int tn = (t + 1 < SEQ) ? (t + 1) : t;
            u_pref = U[((size_t)tn * BATCH + (b0 + rb)) * HID + j0 + rj];  // prefetch
        }
        __syncthreads();

        // ---- phase 3: per-wave autonomous gather of h_{t+1} ----
        if (t + 1 < SEQ) {
            float v;
            if (ownwave) {
                v = own[gb][gk & 63];            // own block's output, via LDS
            } else {
                const u64* slot = hb + p * PSTRIDE + gslot;
                u64 pkt;
                int it = 0;
                do {
                    pkt = __hip_atomic_load(slot, __ATOMIC_RELAXED,
                                            __HIP_MEMORY_SCOPE_AGENT);
                } while ((u32)pkt != tag && ++it < (1 << 14));  // fail fast, no hang
                v = tanhf(__uint_as_float((u32)(pkt >> 32)));
            }
            scratch[kq][jl] = v;   // same-wave write->read, ds-ordered
        }
    }

    // ---- tail: s==0 blocks assemble h_SEQ for hT (slots stay valid) ----
    if (s == 0) {
        const int k = tid >> 1, b = tid & 1;     // 1024 threads <-> 512k x 2b
        const u32 tag = (u32)SEQ;
        const int p = SEQ & 1;                   // parity of final publish
        const u64* slot = hb + p * PSTRIDE
                             + (((size_t)g * SLICES + (k >> 6)) * 2 + b) * JW + (k & 63);
        u64 pkt;
        int it = 0;
        do {
            pkt = __hip_atomic_load(slot, __ATOMIC_RELAXED, __HIP_MEMORY_SCOPE_AGENT);
        } while ((u32)pkt != tag && ++it < (1 << 14));
        hT[(size_t)(b0 + b) * HID + k] = tanhf(__uint_as_float((u32)(pkt >> 32)));
    }
}

// ---------------------------------------------------------------------------
// Launch
// ---------------------------------------------------------------------------
extern "C" void kernel_launch(void* const* d_in, const int* in_sizes, int n_in,
                              void* d_out, int out_size, void* d_ws, size_t ws_size,
                              hipStream_t stream) {
    (void)in_sizes; (void)n_in; (void)out_size; (void)ws_size;

    const float* x      = (const float*)d_in[0];   // (S,B,I)
    const float* hx     = (const float*)d_in[1];   // (2,B,H)
    const float* W_ih0  = (const float*)d_in[2];   // (H,I)
    const float* W_hh0  = (const float*)d_in[3];   // (H,H)
    const float* b_ih0  = (const float*)d_in[4];   // (H,)
    const float* b_hh0  = (const float*)d_in[5];   // (H,)
    const float* W_ih1  = (const float*)d_in[6];   // (H,H)
    const float* W_hh1  = (const float*)d_in[7];   // (H,H)
    const float* b_ih1  = (const float*)d_in[8];   // (H,)
    const float* b_hh1  = (const float*)d_in[9];   // (H,)

    float* out = (float*)d_out;
    float* y1   = out;                                  // (S,B,H)
    float* hT0  = out + (size_t)SEQ * BATCH * HID;      // (B,H)
    float* hT1  = hT0 + (size_t)BATCH * HID;            // (B,H)

    const size_t HB_ELTS = 2 * PSTRIDE;                 // 65536 u64 = 512 KB/layer

    // Workspace: Wt0 (1MB) | Wt1 (1MB) | hb0 (512K) | hb1 (512K) | U0 (128MB)
    float* Wt0 = (float*)d_ws;
    float* Wt1 = Wt0 + (size_t)HID * HID;
    u64* hb0 = (u64*)(Wt1 + (size_t)HID * HID);
    u64* hb1 = hb0 + HB_ELTS;
    float* U0 = (float*)(hb1 + HB_ELTS);

    // zero both slot regions every launch (tag 0 never matches; agent-scope
    // stores write through, so no stale dirty lines survive across runs)
    hipMemsetAsync(hb0, 0, 2 * HB_ELTS * sizeof(u64), stream);

    // 1. transpose W_hh for both layers
    transposeW<<<256, 256, 0, stream>>>(W_hh0, Wt0);
    transposeW<<<256, 256, 0, stream>>>(W_hh1, Wt1);

    // 2. Layer 0 input GEMM: U0 = x @ W_ih0^T + b_ih0 + b_hh0
    gemm_bias<<<(MROWS / BM) * (HID / BN), 256, 0, stream>>>(x, W_ih0, b_ih0, b_hh0, U0);

    // 3. Layer 0 recurrence
    rnn_rec5<<<NGROUPS * SLICES, 1024, 0, stream>>>(U0, Wt0, hx, hT0, hb0);

    // 4. Layer 1 input GEMM: y1 = y0 @ W_ih1^T + b_ih1 + b_hh1
    gemm_bias<<<(MROWS / BM) * (HID / BN), 256, 0, stream>>>(U0, W_ih1, b_ih1, b_hh1, y1);

    // 5. Layer 1 recurrence
    rnn_rec5<<<NGROUPS * SLICES, 1024, 0, stream>>>(y1, Wt1, hx + (size_t)BATCH * HID, hT1, hb1);
}